// Round 11
// baseline (331.193 us; speedup 1.0000x reference)
//
#include <hip/hip_runtime.h>
#include <math.h>

#define HW 512
#define NB 16
#define TX 64            // tile width
#define TY 128           // tile height
#define LDSW 72          // TX + 8 (4-col halo each side, float4-aligned)
#define LDSH 134         // TY + 6
#define N_PIX (NB * HW * HW)   // 4194304
#define NBLK (8 * 4 * NB)      // 512 blocks: co-residency guaranteed (>=2/CU)

// Force a float into an SGPR (uniform across wave).
__device__ __forceinline__ float sgpr_f(float v) {
    return __uint_as_float(__builtin_amdgcn_readfirstlane(__float_as_uint(v)));
}

// Single fused kernel. 512 blocks of 256 threads; thread = 1 column x 32 rows.
// dif identity: sum w*relu(v-c) = sum w*max(v,c) - c*sum(w).
// Rolling finalize keeps ratio[32] in registers; after a device-scope
// atomic-counter barrier (all 512 blocks co-resident by construction:
// LDS 38.6KB -> 4 blocks/CU, launch_bounds(256,2) -> >=2 blocks/CU),
// each block sums the 512 partials and writes the mask from registers.
__global__ __launch_bounds__(256, 2) void li_fused(
    const float* __restrict__ x, const float* __restrict__ kw,
    float* __restrict__ out_mask, float* __restrict__ out_avg,
    float* __restrict__ out_dif, float* __restrict__ partials,
    unsigned int* __restrict__ ctr)
{
    __shared__ float tile[LDSH * LDSW];   // 38592 B
    __shared__ float wsum[4];
    __shared__ float s_inv;

    const int tid = threadIdx.x;
    const int bx = blockIdx.x, by = blockIdx.y, b = blockIdx.z;
    const int x0 = bx * TX, y0 = by * TY;
    const float* xb = x + (size_t)b * (HW * HW);

    // 49 weights pinned to SGPRs; W = sum (center weight is 0).
    float w[49];
    float W = 0.f;
#pragma unroll
    for (int i = 0; i < 49; i++) { w[i] = sgpr_f(kw[i]); W += w[i]; }

    // Stage 134 x 72 tile with zero halo, float4 granularity.
    for (int idx = tid; idx < LDSH * (LDSW / 4); idx += 256) {
        int r = idx / (LDSW / 4);
        int c4 = idx - r * (LDSW / 4);
        int gy = y0 - 3 + r;
        int gx = x0 - 4 + c4 * 4;
        float4 v = make_float4(0.f, 0.f, 0.f, 0.f);
        if ((unsigned)gy < HW && (unsigned)gx < HW)
            v = *(const float4*)(xb + gy * HW + gx);
        *(float4*)&tile[r * LDSW + c4 * 4] = v;
    }
    __syncthreads();

    const int tx  = tid & 63;         // column within tile
    const int ty0 = (tid >> 6) * 32;  // first of 32 output rows

    float cen[32], dif[32], bsum[32], ratio[32];
#pragma unroll
    for (int p = 0; p < 32; p++) {
        cen[p] = tile[(ty0 + p + 3) * LDSW + tx + 4];
        dif[p] = 0.f; bsum[p] = 0.f;
    }

    const size_t base = (size_t)b * (HW * HW) + (size_t)(y0 + ty0) * HW + x0 + tx;
    float ss = 0.f;

    // Software-pipelined row stream; row r feeds pixels p with di = r-p in [0,7).
    float vc[7], vn[7];
#pragma unroll
    for (int dj = 0; dj < 7; dj++)
        vc[dj] = tile[ty0 * LDSW + tx + 1 + dj];

#pragma unroll
    for (int r = 0; r < 38; r++) {
        if (r < 37) {
#pragma unroll
            for (int dj = 0; dj < 7; dj++)
                vn[dj] = tile[(ty0 + r + 1) * LDSW + tx + 1 + dj];
        }

        float rs = ((vc[0] + vc[1]) + (vc[2] + vc[3])) + ((vc[4] + vc[5]) + vc[6]);
#pragma unroll
        for (int p = 0; p < 32; p++) {
            const int di = r - p;
            if (di >= 0 && di < 7) {
                bsum[p] += rs;
#pragma unroll
                for (int dj = 0; dj < 7; dj++) {
                    if (di == 3 && dj == 3) continue;   // center weight == 0
                    dif[p] = fmaf(w[di * 7 + dj], fmaxf(vc[dj], cen[p]), dif[p]);
                }
            }
        }

        // Pixel p = r-6 complete: store avg/dif now, keep ratio in registers.
        if (r >= 6) {
            const int p = r - 6;
            float avg = __expf(-bsum[p] * (1.0f / 49.0f));
            float d = fmaf(-W, cen[p], dif[p]);      // subtract c*sum(w)
            float sp = 0.1f * avg + 0.9f * d;        // > 0 always
            size_t gi = base + (size_t)p * HW;
            out_avg[gi] = avg;
            out_dif[gi] = d;
            ratio[p] = cen[p] * __builtin_amdgcn_rcpf(sp);
            ss = fmaf(sp, sp, ss);
        }

#pragma unroll
        for (int dj = 0; dj < 7; dj++) vc[dj] = vn[dj];
    }

    // Block-level reduce of ss, publish partial, device-scope barrier.
#pragma unroll
    for (int off = 32; off > 0; off >>= 1)
        ss += __shfl_down(ss, off, 64);
    if ((tid & 63) == 0) wsum[tid >> 6] = ss;
    __syncthreads();
    if (tid == 0) {
        const int flat = bx + 8 * (by + 4 * b);
        __hip_atomic_store(&partials[flat],
                           (wsum[0] + wsum[1]) + (wsum[2] + wsum[3]),
                           __ATOMIC_RELAXED, __HIP_MEMORY_SCOPE_AGENT);
        __hip_atomic_fetch_add(ctr, 1u, __ATOMIC_RELEASE,
                               __HIP_MEMORY_SCOPE_AGENT);
        while (__hip_atomic_load(ctr, __ATOMIC_ACQUIRE,
                                 __HIP_MEMORY_SCOPE_AGENT) < NBLK)
            __builtin_amdgcn_s_sleep(8);
    }
    __syncthreads();

    // Every block sums the 512 partials itself (2 device-scope loads/thread).
    float s = __hip_atomic_load(&partials[tid], __ATOMIC_RELAXED,
                                __HIP_MEMORY_SCOPE_AGENT)
            + __hip_atomic_load(&partials[tid + 256], __ATOMIC_RELAXED,
                                __HIP_MEMORY_SCOPE_AGENT);
#pragma unroll
    for (int off = 32; off > 0; off >>= 1)
        s += __shfl_down(s, off, 64);
    if ((tid & 63) == 0) wsum[tid >> 6] = s;
    __syncthreads();
    if (tid == 0)
        s_inv = 1.0f / sqrtf((wsum[0] + wsum[1]) + (wsum[2] + wsum[3]));
    __syncthreads();

    const float inv = s_inv;
#pragma unroll
    for (int p = 0; p < 32; p++)
        out_mask[base + (size_t)p * HW] = (ratio[p] > inv) ? 1.f : 0.f;
}

extern "C" void kernel_launch(void* const* d_in, const int* in_sizes, int n_in,
                              void* d_out, int out_size, void* d_ws, size_t ws_size,
                              hipStream_t stream) {
    const float* x  = (const float*)d_in[0];
    const float* kw = (const float*)d_in[1];
    float* out  = (float*)d_out;
    float* mask = out;
    float* avg  = out + N_PIX;
    float* dif  = out + 2 * (size_t)N_PIX;
    float* partials = (float*)d_ws;                 // [0, NBLK)
    unsigned int* ctr = (unsigned int*)d_ws + NBLK; // one counter

    hipMemsetAsync(ctr, 0, sizeof(unsigned int), stream);

    dim3 g(HW / TX, HW / TY, NB);   // 8 x 4 x 16 = 512 blocks
    li_fused<<<g, 256, 0, stream>>>(x, kw, mask, avg, dif, partials, ctr);
}